// Round 2
// baseline (1444.233 us; speedup 1.0000x reference)
//
#include <hip/hip_runtime.h>
#include <hip/hip_bf16.h>
#include <stdint.h>

typedef unsigned int uint;

constexpr int NN = 8192;     // nodes
constexpr int NE = 24576;    // edges
constexpr int DF = 64;       // features per node
constexpr int NQ = 16;       // qubits (output cols)
constexpr float PI_F = 3.14159265358979f;

// ---------------------------------------------------------------------------
// All tensors fp32 (reference uses jnp.float32; harness contract maps float32
// -> const float*). Round-1 crash forensics: bf16 interpretation left idx
// entries poisoned -> negative node -> memory fault.
//
// workspace layout (bytes):
//   [0..8)              : uint mm[2]  (min bits, max bits; h>=0 so unsigned order ok)
//   [256..256+4*NE)     : int idx_o[NE]
//   [..+4*NE)           : int idx_i[NE]
// total ~197 KB. Un-normalized h lives in d_out (rescaled in-place).
// ---------------------------------------------------------------------------

__global__ void init_minmax_kernel(uint* mm) {
    if (threadIdx.x == 0) {
        mm[0] = 0x7F800000u;  // +inf bits -> running min start
        mm[1] = 0u;           // 0.0 -> running max start (h >= 0)
    }
}

// Scan one incidence matrix [NN, NE] fp32 row-major. Exactly one 1.0 per
// column; record its row. One float4 (16B) per thread, fully coalesced.
// NE % 4 == 0 so a float4 never crosses a row boundary.
__global__ __launch_bounds__(256) void find_idx_kernel(
    const uint4* __restrict__ M, int* __restrict__ idx)
{
    int i = blockIdx.x * 256 + threadIdx.x;     // < 50,331,648
    uint4 v = M[i];                             // 4 floats as bits
    if ((v.x | v.y | v.z | v.w) == 0u) return;  // overwhelmingly common path
    int base = i * 4;                           // flat element index (<2^31)
    int n = base / NE;                          // row (compiler magic-mul)
    int e0 = base - n * NE;                     // col of first element
    if (v.x) idx[e0 + 0] = n;                   // 1.0f = 0x3F800000 != 0
    if (v.y) idx[e0 + 1] = n;
    if (v.z) idx[e0 + 2] = n;
    if (v.w) idx[e0 + 3] = n;
}

// Edge MLP: 16 threads per edge (thread q computes h[e][q]).
// Block = 256 threads = 16 edges. W (128x16) staged in LDS.
__global__ __launch_bounds__(256) void edge_mlp_kernel(
    const float* __restrict__ X,      // fp32 [NN, DF]
    const float* __restrict__ W,      // fp32 [2*DF, NQ]
    const float* __restrict__ bias,   // fp32 [NQ]
    const int* __restrict__ idx_o,
    const int* __restrict__ idx_i,
    float* __restrict__ h,            // fp32 [NE, NQ] (= d_out, un-normalized)
    uint* __restrict__ mm)
{
    __shared__ float Wl[2 * DF * NQ];       // 8 KB, layout [d*NQ + q]
    __shared__ float bl[NQ];
    __shared__ float Bl[16][2 * DF + 4];    // 16 edges x 132 floats (pad: banks 0/4/8/12)
    __shared__ float sred[8];               // per-wave min[0..3], max[4..7]

    const int tid = threadIdx.x;
    const int q   = tid & 15;
    const int eg  = tid >> 4;               // edge within block
    const int e   = blockIdx.x * 16 + eg;

    // stage W, bias -> LDS
    for (int i = tid; i < 2 * DF * NQ; i += 256)
        Wl[i] = W[i];
    if (tid < NQ)
        bl[tid] = bias[tid];

    // gather B[e] = concat(X[idx_o[e]], X[idx_i[e]]) into LDS.
    // 16 threads x 8 floats (2x float4) each = 128 features.
    const int io = idx_o[e] & (NN - 1);     // clamp: bug -> wrong answer, not fault
    const int ii = idx_i[e] & (NN - 1);
    const int r  = q >> 3;                  // 0: o-row, 1: i-row
    const int c  = q & 7;                   // 8-float chunk within the 64-float row
    const int node = r ? ii : io;
    const float4* src = (const float4*)(X + node * DF) + c * 2;
    float4 v0 = src[0];
    float4 v1 = src[1];
    float* bdst = &Bl[eg][q * 8];           // q*8 == r*64 + c*8
    ((float4*)bdst)[0] = v0;
    ((float4*)bdst)[1] = v1;

    __syncthreads();

    // h[e][q] = relu(b[q] + sum_d B[d] * W[d][q])
    float acc = bl[q];
    const float* brow = Bl[eg];
#pragma unroll 8
    for (int d = 0; d < 2 * DF; ++d)
        acc = fmaf(brow[d], Wl[d * NQ + q], acc);

    float hv = fmaxf(acc, 0.0f);
    h[e * NQ + q] = hv;                     // blockIdx*256 + tid: coalesced

    // global min/max: wave shuffle reduce -> LDS -> one atomic pair per block
    float lmin = hv, lmax = hv;
#pragma unroll
    for (int off = 32; off > 0; off >>= 1) {
        lmin = fminf(lmin, __shfl_down(lmin, off));
        lmax = fmaxf(lmax, __shfl_down(lmax, off));
    }
    const int wave = tid >> 6;
    if ((tid & 63) == 0) { sred[wave] = lmin; sred[4 + wave] = lmax; }
    __syncthreads();
    if (tid == 0) {
        float m0 = fminf(fminf(sred[0], sred[1]), fminf(sred[2], sred[3]));
        float m1 = fmaxf(fmaxf(sred[4], sred[5]), fmaxf(sred[6], sred[7]));
        atomicMin(&mm[0], __float_as_uint(m0));  // h >= 0: bits are order-preserving
        atomicMax(&mm[1], __float_as_uint(m1));
    }
}

// out = (h - lo) / (hi - lo) * pi, in-place on d_out. 4 elems/thread.
__global__ __launch_bounds__(256) void rescale_kernel(
    float4* __restrict__ h, const uint* __restrict__ mm)
{
    int i = blockIdx.x * 256 + threadIdx.x;   // NE*NQ/4 = 98304 elems
    float lo = __uint_as_float(mm[0]);
    float hi = __uint_as_float(mm[1]);
    float s  = PI_F / (hi - lo);
    float4 v = h[i];
    v.x = (v.x - lo) * s;
    v.y = (v.y - lo) * s;
    v.z = (v.z - lo) * s;
    v.w = (v.w - lo) * s;
    h[i] = v;
}

extern "C" void kernel_launch(void* const* d_in, const int* in_sizes, int n_in,
                              void* d_out, int out_size, void* d_ws, size_t ws_size,
                              hipStream_t stream) {
    // setup_inputs order: X, Ri, Ro, W_in, b_in (all fp32)
    const float* X  = (const float*)d_in[0];
    const float* Ri = (const float*)d_in[1];
    const float* Ro = (const float*)d_in[2];
    const float* W  = (const float*)d_in[3];
    const float* b  = (const float*)d_in[4];
    float* out = (float*)d_out;

    char* ws = (char*)d_ws;
    uint* mm    = (uint*)ws;
    int*  idx_o = (int*)(ws + 256);
    int*  idx_i = idx_o + NE;

    init_minmax_kernel<<<1, 64, 0, stream>>>(mm);

    // bo = Ro^T X -> idx_o ;  bi = Ri^T X -> idx_i  (B = [bo | bi])
    const int vec_per_mat = NN * (NE / 4);        // 50,331,648 float4 loads
    find_idx_kernel<<<vec_per_mat / 256, 256, 0, stream>>>((const uint4*)Ro, idx_o);
    find_idx_kernel<<<vec_per_mat / 256, 256, 0, stream>>>((const uint4*)Ri, idx_i);

    edge_mlp_kernel<<<NE / 16, 256, 0, stream>>>(X, W, b, idx_o, idx_i, out, mm);

    rescale_kernel<<<(NE * NQ / 4) / 256, 256, 0, stream>>>((float4*)out, mm);
}

// Round 3
// 1419.782 us; speedup vs baseline: 1.0172x; 1.0172x over previous
//
#include <hip/hip_runtime.h>
#include <hip/hip_bf16.h>
#include <stdint.h>

typedef unsigned int uint;
typedef uint uint4v __attribute__((ext_vector_type(4)));

constexpr int NN = 8192;     // nodes
constexpr int NE = 24576;    // edges
constexpr int DF = 64;       // features per node
constexpr int NQ = 16;       // qubits (output cols)
constexpr float PI_F = 3.14159265358979f;

// ---------------------------------------------------------------------------
// All tensors fp32. Algorithm: incidence matrices have exactly one 1.0 per
// edge-column -> Ro^T X / Ri^T X are gathers. Scan 805 MB x2 once to recover
// per-edge node indices (the mandatory-traffic roofline: 1.61 GB ~= 256 us),
// then a tiny per-edge MLP + global min-max rescale.
//
// workspace layout (bytes):
//   [0..8)            : uint mm[2]  (min/max bits; h>=0 so unsigned order ok)
//   [256..256+4*NE)   : int idx_o[NE]
//   [..+4*NE)         : int idx_i[NE]
// Un-normalized h lives in d_out (rescaled in-place).
// ---------------------------------------------------------------------------

// Fused scan of both incidence matrices [NN, NE] fp32 row-major.
// grid = (6 blocks/row, NN rows, 2 matrices); 4 x float4 nontemporal loads
// per thread (64 B), fully coalesced, no integer division anywhere.
__global__ __launch_bounds__(256) void scan_idx_kernel(
    const uint4v* __restrict__ Mo, const uint4v* __restrict__ Mi,
    int* __restrict__ idx_o, int* __restrict__ idx_i,
    uint* __restrict__ mm)
{
    if ((blockIdx.x | blockIdx.y | blockIdx.z | threadIdx.x) == 0) {
        mm[0] = 0x7F800000u;  // +inf bits -> running min start
        mm[1] = 0u;           // 0.0f -> running max start (h >= 0)
    }
    const uint4v* __restrict__ M = blockIdx.z ? Mi : Mo;
    int* __restrict__ idx        = blockIdx.z ? idx_i : idx_o;

    const int row  = blockIdx.y;
    const int base = row * (NE / 4);                    // float4 units, < 2^26
    const int c0   = blockIdx.x * 1024 + threadIdx.x;   // float4 col in row
#pragma unroll
    for (int j = 0; j < 4; ++j) {
        const int c = c0 + j * 256;
        uint4v v = __builtin_nontemporal_load(&M[base + c]);
        if (v.x | v.y | v.z | v.w) {                    // rare path (1/NN cols)
            const int e0 = c * 4;
            if (v.x) idx[e0 + 0] = row;                 // 1.0f bits != 0
            if (v.y) idx[e0 + 1] = row;
            if (v.z) idx[e0 + 2] = row;
            if (v.w) idx[e0 + 3] = row;
        }
    }
}

// Edge MLP: 16 threads per edge (thread q computes h[e][q]).
// Block = 256 threads = 16 edges. W (128x16) staged in LDS.
__global__ __launch_bounds__(256) void edge_mlp_kernel(
    const float* __restrict__ X,      // fp32 [NN, DF]  (2 MB, L2-resident)
    const float* __restrict__ W,      // fp32 [2*DF, NQ]
    const float* __restrict__ bias,   // fp32 [NQ]
    const int* __restrict__ idx_o,
    const int* __restrict__ idx_i,
    float* __restrict__ h,            // fp32 [NE, NQ] (= d_out, un-normalized)
    uint* __restrict__ mm)
{
    __shared__ float Wl[2 * DF * NQ];       // 8 KB, layout [d*NQ + q]
    __shared__ float bl[NQ];
    __shared__ float Bl[16][2 * DF + 4];    // pad: consecutive q hit distinct banks
    __shared__ float sred[8];               // per-wave min[0..3], max[4..7]

    const int tid = threadIdx.x;
    const int q   = tid & 15;
    const int eg  = tid >> 4;               // edge within block
    const int e   = blockIdx.x * 16 + eg;

    for (int i = tid; i < 2 * DF * NQ; i += 256)
        Wl[i] = W[i];
    if (tid < NQ)
        bl[tid] = bias[tid];

    // gather B[e] = concat(X[idx_o[e]], X[idx_i[e]]): 16 thr x 8 floats each.
    const int io = idx_o[e] & (NN - 1);     // clamp: bug -> wrong answer, not fault
    const int ii = idx_i[e] & (NN - 1);
    const int r  = q >> 3;                  // 0: o-row, 1: i-row
    const int c  = q & 7;                   // 8-float chunk within 64-float row
    const int node = r ? ii : io;
    const float4* src = (const float4*)(X + node * DF) + c * 2;
    float4 v0 = src[0];
    float4 v1 = src[1];
    float* bdst = &Bl[eg][q * 8];           // q*8 == r*64 + c*8
    ((float4*)bdst)[0] = v0;
    ((float4*)bdst)[1] = v1;

    __syncthreads();

    float acc = bl[q];
    const float* brow = Bl[eg];
#pragma unroll 8
    for (int d = 0; d < 2 * DF; ++d)
        acc = fmaf(brow[d], Wl[d * NQ + q], acc);

    float hv = fmaxf(acc, 0.0f);
    h[e * NQ + q] = hv;                     // blockIdx*256 + tid: coalesced

    // global min/max: wave shuffle -> LDS -> one atomic pair per block
    float lmin = hv, lmax = hv;
#pragma unroll
    for (int off = 32; off > 0; off >>= 1) {
        lmin = fminf(lmin, __shfl_down(lmin, off));
        lmax = fmaxf(lmax, __shfl_down(lmax, off));
    }
    const int wave = tid >> 6;
    if ((tid & 63) == 0) { sred[wave] = lmin; sred[4 + wave] = lmax; }
    __syncthreads();
    if (tid == 0) {
        float m0 = fminf(fminf(sred[0], sred[1]), fminf(sred[2], sred[3]));
        float m1 = fmaxf(fmaxf(sred[4], sred[5]), fmaxf(sred[6], sred[7]));
        atomicMin(&mm[0], __float_as_uint(m0));  // h >= 0: bits order-preserving
        atomicMax(&mm[1], __float_as_uint(m1));
    }
}

// out = (h - lo) / (hi - lo) * pi, in-place on d_out. 4 elems/thread.
__global__ __launch_bounds__(256) void rescale_kernel(
    float4* __restrict__ h, const uint* __restrict__ mm)
{
    int i = blockIdx.x * 256 + threadIdx.x;   // NE*NQ/4 = 98304 elems
    float lo = __uint_as_float(mm[0]);
    float hi = __uint_as_float(mm[1]);
    float s  = PI_F / (hi - lo);
    float4 v = h[i];
    v.x = (v.x - lo) * s;
    v.y = (v.y - lo) * s;
    v.z = (v.z - lo) * s;
    v.w = (v.w - lo) * s;
    h[i] = v;
}

extern "C" void kernel_launch(void* const* d_in, const int* in_sizes, int n_in,
                              void* d_out, int out_size, void* d_ws, size_t ws_size,
                              hipStream_t stream) {
    // setup_inputs order: X, Ri, Ro, W_in, b_in (all fp32)
    const float* X  = (const float*)d_in[0];
    const float* Ri = (const float*)d_in[1];
    const float* Ro = (const float*)d_in[2];
    const float* W  = (const float*)d_in[3];
    const float* b  = (const float*)d_in[4];
    float* out = (float*)d_out;

    char* ws = (char*)d_ws;
    uint* mm    = (uint*)ws;
    int*  idx_o = (int*)(ws + 256);
    int*  idx_i = idx_o + NE;

    // bo = Ro^T X -> idx_o ;  bi = Ri^T X -> idx_i  (B = [bo | bi])
    scan_idx_kernel<<<dim3(NE / 4 / 1024, NN, 2), 256, 0, stream>>>(
        (const uint4v*)Ro, (const uint4v*)Ri, idx_o, idx_i, mm);

    edge_mlp_kernel<<<NE / 16, 256, 0, stream>>>(X, W, b, idx_o, idx_i, out, mm);

    rescale_kernel<<<(NE * NQ / 4) / 256, 256, 0, stream>>>((float4*)out, mm);
}

// Round 4
// 1418.161 us; speedup vs baseline: 1.0184x; 1.0011x over previous
//
#include <hip/hip_runtime.h>
#include <hip/hip_bf16.h>
#include <stdint.h>

typedef unsigned int uint;
typedef uint uint4v __attribute__((ext_vector_type(4)));

constexpr int NN = 8192;     // nodes
constexpr int NE = 24576;    // edges
constexpr int DF = 64;       // features per node
constexpr int NQ = 16;       // qubits (output cols)
constexpr float PI_F = 3.14159265358979f;

// ---------------------------------------------------------------------------
// All tensors fp32. Incidence matrices have exactly one 1.0 per edge-column
// -> Ro^T X / Ri^T X are gathers. Scan 805 MB x2 once to recover per-edge
// node indices (mandatory traffic: 1.61 GB ~= 255 us @ 6.3 TB/s -- the
// controllable roofline), then a tiny per-edge MLP + global min-max rescale.
// Timed window also contains ~1.1 ms of harness resets (3.2 GB ws poison
// fill + 1.6 GB input restore) -- not controllable from here.
//
// workspace layout (bytes):
//   [0..8)            : uint mm[2]  (min/max bits; h>=0 so unsigned order ok)
//   [256..256+4*NE)   : int idx_o[NE]
//   [..+4*NE)         : int idx_i[NE]
// Un-normalized h lives in d_out (rescaled in-place).
// ---------------------------------------------------------------------------

// Fused scan of both incidence matrices [NN, NE] fp32 row-major.
// grid = (3 blocks/row, NN rows, 2 matrices). Each thread: 8 x float4
// nontemporal loads (128 B) issued back-to-back for deep vmcnt pipelining,
// then checked. Fully coalesced (1 KB per wave-instruction), no int division.
__global__ __launch_bounds__(256) void scan_idx_kernel(
    const uint4v* __restrict__ Mo, const uint4v* __restrict__ Mi,
    int* __restrict__ idx_o, int* __restrict__ idx_i,
    uint* __restrict__ mm)
{
    if ((blockIdx.x | blockIdx.y | blockIdx.z | threadIdx.x) == 0) {
        mm[0] = 0x7F800000u;  // +inf bits -> running min start
        mm[1] = 0u;           // 0.0f -> running max start (h >= 0)
    }
    const uint4v* __restrict__ M = blockIdx.z ? Mi : Mo;
    int* __restrict__ idx        = blockIdx.z ? idx_i : idx_o;

    const int row  = blockIdx.y;
    const int base = row * (NE / 4);                    // float4 units
    const int c0   = blockIdx.x * 2048 + threadIdx.x;   // float4 col in row

    uint4v v[8];
#pragma unroll
    for (int j = 0; j < 8; ++j)
        v[j] = __builtin_nontemporal_load(&M[base + c0 + j * 256]);

#pragma unroll
    for (int j = 0; j < 8; ++j) {
        if (v[j].x | v[j].y | v[j].z | v[j].w) {        // rare path (1/NN cols)
            const int e0 = (c0 + j * 256) * 4;
            if (v[j].x) idx[e0 + 0] = row;              // 1.0f bits != 0
            if (v[j].y) idx[e0 + 1] = row;
            if (v[j].z) idx[e0 + 2] = row;
            if (v[j].w) idx[e0 + 3] = row;
        }
    }
}

// Edge MLP: 16 threads per edge (thread q computes h[e][q]).
// Block = 256 threads = 16 edges. W (128x16) staged in LDS.
__global__ __launch_bounds__(256) void edge_mlp_kernel(
    const float* __restrict__ X,      // fp32 [NN, DF]  (2 MB, L2-resident)
    const float* __restrict__ W,      // fp32 [2*DF, NQ]
    const float* __restrict__ bias,   // fp32 [NQ]
    const int* __restrict__ idx_o,
    const int* __restrict__ idx_i,
    float* __restrict__ h,            // fp32 [NE, NQ] (= d_out, un-normalized)
    uint* __restrict__ mm)
{
    __shared__ float Wl[2 * DF * NQ];       // 8 KB, layout [d*NQ + q]
    __shared__ float bl[NQ];
    __shared__ float Bl[16][2 * DF + 4];    // pad: consecutive q hit distinct banks
    __shared__ float sred[8];               // per-wave min[0..3], max[4..7]

    const int tid = threadIdx.x;
    const int q   = tid & 15;
    const int eg  = tid >> 4;               // edge within block
    const int e   = blockIdx.x * 16 + eg;

    for (int i = tid; i < 2 * DF * NQ; i += 256)
        Wl[i] = W[i];
    if (tid < NQ)
        bl[tid] = bias[tid];

    // gather B[e] = concat(X[idx_o[e]], X[idx_i[e]]): 16 thr x 8 floats each.
    const int io = idx_o[e] & (NN - 1);     // clamp: bug -> wrong answer, not fault
    const int ii = idx_i[e] & (NN - 1);
    const int r  = q >> 3;                  // 0: o-row, 1: i-row
    const int c  = q & 7;                   // 8-float chunk within 64-float row
    const int node = r ? ii : io;
    const float4* src = (const float4*)(X + node * DF) + c * 2;
    float4 v0 = src[0];
    float4 v1 = src[1];
    float* bdst = &Bl[eg][q * 8];           // q*8 == r*64 + c*8
    ((float4*)bdst)[0] = v0;
    ((float4*)bdst)[1] = v1;

    __syncthreads();

    float acc = bl[q];
    const float* brow = Bl[eg];
#pragma unroll 8
    for (int d = 0; d < 2 * DF; ++d)
        acc = fmaf(brow[d], Wl[d * NQ + q], acc);

    float hv = fmaxf(acc, 0.0f);
    h[e * NQ + q] = hv;                     // blockIdx*256 + tid: coalesced

    // global min/max: wave shuffle -> LDS -> one atomic pair per block
    float lmin = hv, lmax = hv;
#pragma unroll
    for (int off = 32; off > 0; off >>= 1) {
        lmin = fminf(lmin, __shfl_down(lmin, off));
        lmax = fmaxf(lmax, __shfl_down(lmax, off));
    }
    const int wave = tid >> 6;
    if ((tid & 63) == 0) { sred[wave] = lmin; sred[4 + wave] = lmax; }
    __syncthreads();
    if (tid == 0) {
        float m0 = fminf(fminf(sred[0], sred[1]), fminf(sred[2], sred[3]));
        float m1 = fmaxf(fmaxf(sred[4], sred[5]), fmaxf(sred[6], sred[7]));
        atomicMin(&mm[0], __float_as_uint(m0));  // h >= 0: bits order-preserving
        atomicMax(&mm[1], __float_as_uint(m1));
    }
}

// out = (h - lo) / (hi - lo) * pi, in-place on d_out. 4 elems/thread.
__global__ __launch_bounds__(256) void rescale_kernel(
    float4* __restrict__ h, const uint* __restrict__ mm)
{
    int i = blockIdx.x * 256 + threadIdx.x;   // NE*NQ/4 = 98304 elems
    float lo = __uint_as_float(mm[0]);
    float hi = __uint_as_float(mm[1]);
    float s  = PI_F / (hi - lo);
    float4 v = h[i];
    v.x = (v.x - lo) * s;
    v.y = (v.y - lo) * s;
    v.z = (v.z - lo) * s;
    v.w = (v.w - lo) * s;
    h[i] = v;
}

extern "C" void kernel_launch(void* const* d_in, const int* in_sizes, int n_in,
                              void* d_out, int out_size, void* d_ws, size_t ws_size,
                              hipStream_t stream) {
    // setup_inputs order: X, Ri, Ro, W_in, b_in (all fp32)
    const float* X  = (const float*)d_in[0];
    const float* Ri = (const float*)d_in[1];
    const float* Ro = (const float*)d_in[2];
    const float* W  = (const float*)d_in[3];
    const float* b  = (const float*)d_in[4];
    float* out = (float*)d_out;

    char* ws = (char*)d_ws;
    uint* mm    = (uint*)ws;
    int*  idx_o = (int*)(ws + 256);
    int*  idx_i = idx_o + NE;

    // bo = Ro^T X -> idx_o ;  bi = Ri^T X -> idx_i  (B = [bo | bi])
    scan_idx_kernel<<<dim3(NE / 4 / 2048, NN, 2), 256, 0, stream>>>(
        (const uint4v*)Ro, (const uint4v*)Ri, idx_o, idx_i, mm);

    edge_mlp_kernel<<<NE / 16, 256, 0, stream>>>(X, W, b, idx_o, idx_i, out, mm);

    rescale_kernel<<<(NE * NQ / 4) / 256, 256, 0, stream>>>((float4*)out, mm);
}